// Round 1
// baseline (124.655 us; speedup 1.0000x reference)
//
#include <hip/hip_runtime.h>
#include <math.h>

// PolicyGradient_28819230556839: 3-layer post-norm transformer encoder,
// B=8192, S=9, D=3, H=3 (head dim 1), DFF=2048, then logits->softmax->prod->softmax.
// fp32 vector-compute bound (no fp32 MFMA on CDNA4). FFN dominates:
// 2.72 G FMA total -> 34.6 us roofline at 157.3 TF.

constexpr int S   = 9;
constexpr int D   = 3;
constexpr int DFF = 2048;
constexpr int L   = 3;
constexpr int G   = 16;          // threads cooperating on one batch element
constexpr int BLK = 256;         // block size
constexpr int BPB = BLK / G;     // batch elements per block = 16
constexpr int FPT = DFF / G;     // f-values per thread = 128
constexpr float EPS = 1e-5f;

__launch_bounds__(BLK, 2)
__global__ void tf_policy_kernel(const float* __restrict__ x,
                                 const float* __restrict__ Wqkv,
                                 const float* __restrict__ bqkv,
                                 const float* __restrict__ Wo,
                                 const float* __restrict__ bo,
                                 const float* __restrict__ g1,
                                 const float* __restrict__ be1,
                                 const float* __restrict__ W1,
                                 const float* __restrict__ bf1,
                                 const float* __restrict__ W2,
                                 const float* __restrict__ bf2,
                                 const float* __restrict__ g2,
                                 const float* __restrict__ be2,
                                 const float* __restrict__ Wfin,
                                 float* __restrict__ out)
{
    // Two separate float4 arrays: bank(f) = (f*4)%32; with f = i*16+sub the 16
    // lanes land on bank-quads {0,4,...,60}%32 -> 2-way conflict only (free).
    __shared__ float4 s_w1[DFF];   // {W1[f][0..2], bf1[f]}
    __shared__ float4 s_w2[DFF];   // {W2[0][f], W2[1][f], W2[2][f], 0}

    const int tid = threadIdx.x;
    const int grp = tid >> 4;      // which batch element within block
    const int sub = tid & 15;      // lane within the 16-thread group
    const int b   = blockIdx.x * BPB + grp;

    // per-thread hidden state h[9][3]
    float h[S][D];
    {
        const float* xr = x + (size_t)b * (S * D);
        #pragma unroll
        for (int s = 0; s < S; ++s)
            #pragma unroll
            for (int d = 0; d < D; ++d)
                h[s][d] = xr[s * D + d];
    }

    for (int l = 0; l < L; ++l) {
        __syncthreads();   // protect LDS from previous layer's readers
        // ---- stage FFN weights (packed) into LDS ----
        {
            const float* w1p = W1  + (size_t)l * DFF * D;
            const float* b1p = bf1 + (size_t)l * DFF;
            const float* w2p = W2  + (size_t)l * D * DFF;
            for (int i = tid; i < DFF; i += BLK) {
                float4 a;
                a.x = w1p[i * 3 + 0];
                a.y = w1p[i * 3 + 1];
                a.z = w1p[i * 3 + 2];
                a.w = b1p[i];
                s_w1[i] = a;
                float4 c;
                c.x = w2p[i];
                c.y = w2p[DFF + i];
                c.z = w2p[2 * DFF + i];
                c.w = 0.f;
                s_w2[i] = c;
            }
        }
        __syncthreads();

        // ---- attention (redundant across the 16 lanes; tiny: H=3, HD=1) ----
        const float* wq = Wqkv + (size_t)l * (3 * D) * D;   // [9][3]
        const float* bq = bqkv + (size_t)l * (3 * D);
        float o[S][D];
        #pragma unroll
        for (int hh = 0; hh < 3; ++hh) {
            float q[S], k[S], v[S];
            #pragma unroll
            for (int s = 0; s < S; ++s) {
                q[s] = fmaf(wq[hh * 3 + 0], h[s][0],
                       fmaf(wq[hh * 3 + 1], h[s][1],
                       fmaf(wq[hh * 3 + 2], h[s][2], bq[hh])));
                k[s] = fmaf(wq[(3 + hh) * 3 + 0], h[s][0],
                       fmaf(wq[(3 + hh) * 3 + 1], h[s][1],
                       fmaf(wq[(3 + hh) * 3 + 2], h[s][2], bq[3 + hh])));
                v[s] = fmaf(wq[(6 + hh) * 3 + 0], h[s][0],
                       fmaf(wq[(6 + hh) * 3 + 1], h[s][1],
                       fmaf(wq[(6 + hh) * 3 + 2], h[s][2], bq[6 + hh])));
            }
            // head-dim is 1 -> score[qs][ks] = q[qs]*k[ks]; scale = 1/sqrt(1) = 1
            #pragma unroll
            for (int qs = 0; qs < S; ++qs) {
                float sc[S];
                float m = -1e30f;
                #pragma unroll
                for (int ks = 0; ks < S; ++ks) {
                    sc[ks] = q[qs] * k[ks];
                    m = fmaxf(m, sc[ks]);
                }
                float sum = 0.f, av = 0.f;
                #pragma unroll
                for (int ks = 0; ks < S; ++ks) {
                    float e = __expf(sc[ks] - m);
                    sum += e;
                    av = fmaf(e, v[ks], av);
                }
                o[qs][hh] = av / sum;
            }
        }

        // ---- Wo projection + residual + LN1 ----
        {
            const float* wo  = Wo  + (size_t)l * D * D;
            const float* bop = bo  + (size_t)l * D;
            const float* gp  = g1  + (size_t)l * D;
            const float* bp  = be1 + (size_t)l * D;
            #pragma unroll
            for (int s = 0; s < S; ++s) {
                float t[D];
                #pragma unroll
                for (int dd = 0; dd < D; ++dd)
                    t[dd] = h[s][dd] + bop[dd] +
                            fmaf(wo[dd * 3 + 0], o[s][0],
                            fmaf(wo[dd * 3 + 1], o[s][1],
                                 wo[dd * 3 + 2] * o[s][2]));
                float m  = (t[0] + t[1] + t[2]) * (1.f / 3.f);
                float d0 = t[0] - m, d1 = t[1] - m, d2 = t[2] - m;
                float va = (d0 * d0 + d1 * d1 + d2 * d2) * (1.f / 3.f);
                float r  = rsqrtf(va + EPS);
                h[s][0] = fmaf(d0 * r, gp[0], bp[0]);
                h[s][1] = fmaf(d1 * r, gp[1], bp[1]);
                h[s][2] = fmaf(d2 * r, gp[2], bp[2]);
            }
        }

        // ---- FFN: this thread handles f = i*16 + sub, i in [0,128) ----
        float acc[S][D];
        #pragma unroll
        for (int s = 0; s < S; ++s)
            #pragma unroll
            for (int d = 0; d < D; ++d)
                acc[s][d] = 0.f;

        for (int i = 0; i < FPT; ++i) {
            const int f = i * G + sub;
            const float4 w1 = s_w1[f];
            const float4 w2 = s_w2[f];
            #pragma unroll
            for (int s = 0; s < S; ++s) {
                float t = fmaf(w1.x, h[s][0],
                          fmaf(w1.y, h[s][1],
                          fmaf(w1.z, h[s][2], w1.w)));
                t = fmaxf(t, 0.f);
                acc[s][0] = fmaf(w2.x, t, acc[s][0]);
                acc[s][1] = fmaf(w2.y, t, acc[s][1]);
                acc[s][2] = fmaf(w2.z, t, acc[s][2]);
            }
        }

        // ---- butterfly-reduce the 27 partials across the 16 lanes ----
        #pragma unroll
        for (int mask = 1; mask < G; mask <<= 1) {
            #pragma unroll
            for (int s = 0; s < S; ++s)
                #pragma unroll
                for (int d = 0; d < D; ++d)
                    acc[s][d] += __shfl_xor(acc[s][d], mask, 64);
        }

        // ---- bf2 + residual + LN2 ----
        {
            const float* b2p = bf2 + (size_t)l * D;
            const float* gp  = g2  + (size_t)l * D;
            const float* bp  = be2 + (size_t)l * D;
            #pragma unroll
            for (int s = 0; s < S; ++s) {
                float t[D];
                #pragma unroll
                for (int dd = 0; dd < D; ++dd)
                    t[dd] = h[s][dd] + acc[s][dd] + b2p[dd];
                float m  = (t[0] + t[1] + t[2]) * (1.f / 3.f);
                float d0 = t[0] - m, d1 = t[1] - m, d2 = t[2] - m;
                float va = (d0 * d0 + d1 * d1 + d2 * d2) * (1.f / 3.f);
                float r  = rsqrtf(va + EPS);
                h[s][0] = fmaf(d0 * r, gp[0], bp[0]);
                h[s][1] = fmaf(d1 * r, gp[1], bp[1]);
                h[s][2] = fmaf(d2 * r, gp[2], bp[2]);
            }
        }
    }

    // ---- epilogue: z = softmax(h@W) per token, u = prod_s z, softmax(u) ----
    if (sub == 0) {
        float u[S];
        #pragma unroll
        for (int n = 0; n < S; ++n) u[n] = 1.f;
        #pragma unroll
        for (int s = 0; s < S; ++s) {
            float z[S];
            float m = -1e30f;
            #pragma unroll
            for (int n = 0; n < S; ++n) {
                z[n] = fmaf(h[s][0], Wfin[0 * S + n],
                       fmaf(h[s][1], Wfin[1 * S + n],
                            h[s][2] * Wfin[2 * S + n]));
                m = fmaxf(m, z[n]);
            }
            float sum = 0.f;
            #pragma unroll
            for (int n = 0; n < S; ++n) { z[n] = __expf(z[n] - m); sum += z[n]; }
            float inv = 1.f / sum;
            #pragma unroll
            for (int n = 0; n < S; ++n) u[n] *= z[n] * inv;
        }
        float m = -1e30f;
        #pragma unroll
        for (int n = 0; n < S; ++n) m = fmaxf(m, u[n]);
        float e[S];
        float sum = 0.f;
        #pragma unroll
        for (int n = 0; n < S; ++n) { e[n] = __expf(u[n] - m); sum += e[n]; }
        float inv = 1.f / sum;
        float* op = out + (size_t)b * S;
        #pragma unroll
        for (int n = 0; n < S; ++n) op[n] = e[n] * inv;
    }
}

extern "C" void kernel_launch(void* const* d_in, const int* in_sizes, int n_in,
                              void* d_out, int out_size, void* d_ws, size_t ws_size,
                              hipStream_t stream)
{
    const float* x    = (const float*)d_in[0];
    const float* Wqkv = (const float*)d_in[1];
    const float* bqkv = (const float*)d_in[2];
    const float* Wo   = (const float*)d_in[3];
    const float* bo   = (const float*)d_in[4];
    const float* g1   = (const float*)d_in[5];
    const float* be1  = (const float*)d_in[6];
    const float* W1   = (const float*)d_in[7];
    const float* bf1  = (const float*)d_in[8];
    const float* W2   = (const float*)d_in[9];
    const float* bf2  = (const float*)d_in[10];
    const float* g2   = (const float*)d_in[11];
    const float* be2  = (const float*)d_in[12];
    const float* Wfin = (const float*)d_in[13];
    float* out = (float*)d_out;

    const int B = in_sizes[0] / (S * D);       // 8192
    const int nblocks = B / BPB;               // 512

    tf_policy_kernel<<<nblocks, BLK, 0, stream>>>(
        x, Wqkv, bqkv, Wo, bo, g1, be1, W1, bf1, W2, bf2, g2, be2, Wfin, out);
}

// Round 2
// 119.824 us; speedup vs baseline: 1.0403x; 1.0403x over previous
//
#include <hip/hip_runtime.h>
#include <math.h>

// PolicyGradient_28819230556839: 3-layer post-norm transformer encoder,
// B=8192, S=9, D=3, H=3 (head dim 1), DFF=2048, then logits->softmax->prod->softmax.
// fp32 VALU-bound. Scalar v_fma peak = 78.6 TF; packed v_pk_fma_f32 = 157.3 TF.
// R2: pack the FFN (80% of instrs) over f-pairs with v_pk_fma_f32 inline asm.

constexpr int S   = 9;
constexpr int D   = 3;
constexpr int DFF = 2048;
constexpr int L   = 3;
constexpr int G   = 16;          // threads cooperating on one batch element
constexpr int BLK = 256;         // block size
constexpr int BPB = BLK / G;     // batch elements per block = 16
constexpr int FPT = DFF / G;     // f-values per thread = 128
constexpr int PPT = FPT / 2;     // f-pairs per thread = 64
constexpr float EPS = 1e-5f;

typedef float v2f __attribute__((ext_vector_type(2)));
typedef float v4f __attribute__((ext_vector_type(4)));

__device__ __forceinline__ v2f pk_fma(v2f a, v2f b, v2f c) {
    v2f d;
    asm("v_pk_fma_f32 %0, %1, %2, %3" : "=v"(d) : "v"(a), "v"(b), "v"(c));
    return d;
}

__launch_bounds__(BLK, 2)
__global__ void tf_policy_kernel(const float* __restrict__ x,
                                 const float* __restrict__ Wqkv,
                                 const float* __restrict__ bqkv,
                                 const float* __restrict__ Wo,
                                 const float* __restrict__ bo,
                                 const float* __restrict__ g1,
                                 const float* __restrict__ be1,
                                 const float* __restrict__ W1,
                                 const float* __restrict__ bf1,
                                 const float* __restrict__ W2,
                                 const float* __restrict__ bf2,
                                 const float* __restrict__ g2,
                                 const float* __restrict__ be2,
                                 const float* __restrict__ Wfin,
                                 float* __restrict__ out)
{
    // Packed-pair FFN weight layout (pair p covers f=2p, 2p+1):
    //   s_a[p] = {W1[2p][0], W1[2p+1][0], W1[2p][1], W1[2p+1][1]}
    //   s_b[p] = {W1[2p][2], W1[2p+1][2], bf1[2p],   bf1[2p+1]}
    //   s_c[p] = {W2[0][2p], W2[0][2p+1], W2[1][2p], W2[1][2p+1]}
    //   s_d[p] = {W2[2][2p], W2[2][2p+1]}
    // One vaddr (p*16 / p*8) + compile-time offsets; 16B/lane -> 2-way bank
    // alias (free, m136); lanes 16/32/48 share addresses -> broadcast.
    __shared__ v4f s_a[DFF / 2];
    __shared__ v4f s_b[DFF / 2];
    __shared__ v4f s_c[DFF / 2];
    __shared__ v2f s_d[DFF / 2];

    const int tid = threadIdx.x;
    const int grp = tid >> 4;      // which batch element within block
    const int sub = tid & 15;      // lane within the 16-thread group
    const int b   = blockIdx.x * BPB + grp;

    // per-thread hidden state h[9][3]
    float h[S][D];
    {
        const float* xr = x + (size_t)b * (S * D);
        #pragma unroll
        for (int s = 0; s < S; ++s)
            #pragma unroll
            for (int d = 0; d < D; ++d)
                h[s][d] = xr[s * D + d];
    }

    for (int l = 0; l < L; ++l) {
        __syncthreads();   // protect LDS from previous layer's readers
        // ---- stage packed FFN weights into LDS ----
        {
            const float* w1p = W1  + (size_t)l * DFF * D;
            const float* b1p = bf1 + (size_t)l * DFF;
            const float* w2p = W2  + (size_t)l * D * DFF;
            const v2f* w1v = (const v2f*)w1p;
            const v2f* b1v = (const v2f*)b1p;
            const v2f* c0v = (const v2f*)w2p;
            const v2f* c1v = (const v2f*)(w2p + DFF);
            const v2f* c2v = (const v2f*)(w2p + 2 * DFF);
            for (int p = tid; p < DFF / 2; p += BLK) {
                v2f r0 = w1v[3 * p];        // {W1[2p][0], W1[2p][1]}
                v2f r1 = w1v[3 * p + 1];    // {W1[2p][2], W1[2p+1][0]}
                v2f r2 = w1v[3 * p + 2];    // {W1[2p+1][1], W1[2p+1][2]}
                v2f bb = b1v[p];
                v2f c0 = c0v[p];
                v2f c1 = c1v[p];
                v2f c2 = c2v[p];
                s_a[p] = (v4f){r0.x, r1.y, r0.y, r2.x};
                s_b[p] = (v4f){r1.x, r2.y, bb.x, bb.y};
                s_c[p] = (v4f){c0.x, c0.y, c1.x, c1.y};
                s_d[p] = c2;
            }
        }
        __syncthreads();

        // ---- attention (lanes of a wave cover 4 batch elems; H=3, HD=1) ----
        const float* wq = Wqkv + (size_t)l * (3 * D) * D;   // [9][3]
        const float* bq = bqkv + (size_t)l * (3 * D);
        float o[S][D];
        #pragma unroll
        for (int hh = 0; hh < 3; ++hh) {
            float q[S], k[S], v[S];
            #pragma unroll
            for (int s = 0; s < S; ++s) {
                q[s] = fmaf(wq[hh * 3 + 0], h[s][0],
                       fmaf(wq[hh * 3 + 1], h[s][1],
                       fmaf(wq[hh * 3 + 2], h[s][2], bq[hh])));
                k[s] = fmaf(wq[(3 + hh) * 3 + 0], h[s][0],
                       fmaf(wq[(3 + hh) * 3 + 1], h[s][1],
                       fmaf(wq[(3 + hh) * 3 + 2], h[s][2], bq[3 + hh])));
                v[s] = fmaf(wq[(6 + hh) * 3 + 0], h[s][0],
                       fmaf(wq[(6 + hh) * 3 + 1], h[s][1],
                       fmaf(wq[(6 + hh) * 3 + 2], h[s][2], bq[6 + hh])));
            }
            // head-dim 1 -> score[qs][ks] = q[qs]*k[ks]; scale = 1
            #pragma unroll
            for (int qs = 0; qs < S; ++qs) {
                float sc[S];
                float m = -1e30f;
                #pragma unroll
                for (int ks = 0; ks < S; ++ks) {
                    sc[ks] = q[qs] * k[ks];
                    m = fmaxf(m, sc[ks]);
                }
                float sum = 0.f, av = 0.f;
                #pragma unroll
                for (int ks = 0; ks < S; ++ks) {
                    float e = __expf(sc[ks] - m);
                    sum += e;
                    av = fmaf(e, v[ks], av);
                }
                o[qs][hh] = av / sum;
            }
        }

        // ---- Wo projection + residual + LN1 ----
        {
            const float* wo  = Wo  + (size_t)l * D * D;
            const float* bop = bo  + (size_t)l * D;
            const float* gp  = g1  + (size_t)l * D;
            const float* bp  = be1 + (size_t)l * D;
            #pragma unroll
            for (int s = 0; s < S; ++s) {
                float t[D];
                #pragma unroll
                for (int dd = 0; dd < D; ++dd)
                    t[dd] = h[s][dd] + bop[dd] +
                            fmaf(wo[dd * 3 + 0], o[s][0],
                            fmaf(wo[dd * 3 + 1], o[s][1],
                                 wo[dd * 3 + 2] * o[s][2]));
                float m  = (t[0] + t[1] + t[2]) * (1.f / 3.f);
                float d0 = t[0] - m, d1 = t[1] - m, d2 = t[2] - m;
                float va = (d0 * d0 + d1 * d1 + d2 * d2) * (1.f / 3.f);
                float r  = rsqrtf(va + EPS);
                h[s][0] = fmaf(d0 * r, gp[0], bp[0]);
                h[s][1] = fmaf(d1 * r, gp[1], bp[1]);
                h[s][2] = fmaf(d2 * r, gp[2], bp[2]);
            }
        }

        // ---- FFN, packed over f-pairs: p = i*16 + sub, i in [0,64) ----
        v2f hb[S][D];                 // h broadcast to both halves (once)
        #pragma unroll
        for (int s = 0; s < S; ++s)
            #pragma unroll
            for (int d = 0; d < D; ++d)
                hb[s][d] = (v2f){h[s][d], h[s][d]};

        v2f acc2[S][D];
        #pragma unroll
        for (int s = 0; s < S; ++s)
            #pragma unroll
            for (int d = 0; d < D; ++d)
                acc2[s][d] = (v2f){0.f, 0.f};

        #pragma unroll 2
        for (int i = 0; i < PPT; ++i) {
            const int p = i * G + sub;
            const v4f A  = s_a[p];
            const v4f Bv = s_b[p];
            const v4f C  = s_c[p];
            const v2f Dz = s_d[p];
            const v2f w1x = A.xy,  w1y = A.zw;
            const v2f w1z = Bv.xy, w1b = Bv.zw;
            const v2f w2x = C.xy,  w2y = C.zw;
            #pragma unroll
            for (int s = 0; s < S; ++s) {
                v2f t = pk_fma(w1x, hb[s][0],
                        pk_fma(w1y, hb[s][1],
                        pk_fma(w1z, hb[s][2], w1b)));
                t.x = fmaxf(t.x, 0.f);
                t.y = fmaxf(t.y, 0.f);
                acc2[s][0] = pk_fma(C.xy, t, acc2[s][0]);
                acc2[s][1] = pk_fma(w2y, t, acc2[s][1]);
                acc2[s][2] = pk_fma(Dz, t, acc2[s][2]);
                (void)w2x;
            }
        }

        // ---- collapse pair halves, then butterfly-reduce across 16 lanes ----
        float acc[S][D];
        #pragma unroll
        for (int s = 0; s < S; ++s)
            #pragma unroll
            for (int d = 0; d < D; ++d)
                acc[s][d] = acc2[s][d].x + acc2[s][d].y;

        #pragma unroll
        for (int mask = 1; mask < G; mask <<= 1) {
            #pragma unroll
            for (int s = 0; s < S; ++s)
                #pragma unroll
                for (int d = 0; d < D; ++d)
                    acc[s][d] += __shfl_xor(acc[s][d], mask, 64);
        }

        // ---- bf2 + residual + LN2 ----
        {
            const float* b2p = bf2 + (size_t)l * D;
            const float* gp  = g2  + (size_t)l * D;
            const float* bp  = be2 + (size_t)l * D;
            #pragma unroll
            for (int s = 0; s < S; ++s) {
                float t[D];
                #pragma unroll
                for (int dd = 0; dd < D; ++dd)
                    t[dd] = h[s][dd] + acc[s][dd] + b2p[dd];
                float m  = (t[0] + t[1] + t[2]) * (1.f / 3.f);
                float d0 = t[0] - m, d1 = t[1] - m, d2 = t[2] - m;
                float va = (d0 * d0 + d1 * d1 + d2 * d2) * (1.f / 3.f);
                float r  = rsqrtf(va + EPS);
                h[s][0] = fmaf(d0 * r, gp[0], bp[0]);
                h[s][1] = fmaf(d1 * r, gp[1], bp[1]);
                h[s][2] = fmaf(d2 * r, gp[2], bp[2]);
            }
        }
    }

    // ---- epilogue: z = softmax(h@W) per token, u = prod_s z, softmax(u) ----
    if (sub == 0) {
        float u[S];
        #pragma unroll
        for (int n = 0; n < S; ++n) u[n] = 1.f;
        #pragma unroll
        for (int s = 0; s < S; ++s) {
            float z[S];
            float m = -1e30f;
            #pragma unroll
            for (int n = 0; n < S; ++n) {
                z[n] = fmaf(h[s][0], Wfin[0 * S + n],
                       fmaf(h[s][1], Wfin[1 * S + n],
                            h[s][2] * Wfin[2 * S + n]));
                m = fmaxf(m, z[n]);
            }
            float sum = 0.f;
            #pragma unroll
            for (int n = 0; n < S; ++n) { z[n] = __expf(z[n] - m); sum += z[n]; }
            float inv = 1.f / sum;
            #pragma unroll
            for (int n = 0; n < S; ++n) u[n] *= z[n] * inv;
        }
        float m = -1e30f;
        #pragma unroll
        for (int n = 0; n < S; ++n) m = fmaxf(m, u[n]);
        float e[S];
        float sum = 0.f;
        #pragma unroll
        for (int n = 0; n < S; ++n) { e[n] = __expf(u[n] - m); sum += e[n]; }
        float inv = 1.f / sum;
        float* op = out + (size_t)b * S;
        #pragma unroll
        for (int n = 0; n < S; ++n) op[n] = e[n] * inv;
    }
}

extern "C" void kernel_launch(void* const* d_in, const int* in_sizes, int n_in,
                              void* d_out, int out_size, void* d_ws, size_t ws_size,
                              hipStream_t stream)
{
    const float* x    = (const float*)d_in[0];
    const float* Wqkv = (const float*)d_in[1];
    const float* bqkv = (const float*)d_in[2];
    const float* Wo   = (const float*)d_in[3];
    const float* bo   = (const float*)d_in[4];
    const float* g1   = (const float*)d_in[5];
    const float* be1  = (const float*)d_in[6];
    const float* W1   = (const float*)d_in[7];
    const float* bf1  = (const float*)d_in[8];
    const float* W2   = (const float*)d_in[9];
    const float* bf2  = (const float*)d_in[10];
    const float* g2   = (const float*)d_in[11];
    const float* be2  = (const float*)d_in[12];
    const float* Wfin = (const float*)d_in[13];
    float* out = (float*)d_out;

    const int B = in_sizes[0] / (S * D);       // 8192
    const int nblocks = B / BPB;               // 512

    tf_policy_kernel<<<nblocks, BLK, 0, stream>>>(
        x, Wqkv, bqkv, Wo, bo, g1, be1, W1, bf1, W2, bf2, g2, be2, Wfin, out);
}

// Round 3
// 110.015 us; speedup vs baseline: 1.1331x; 1.0892x over previous
//
#include <hip/hip_runtime.h>
#include <math.h>

// PolicyGradient_28819230556839: 3-layer post-norm transformer encoder,
// B=8192, S=9, D=3, H=3 (head dim 1), DFF=2048, then logits->softmax->prod->softmax.
// fp32 VALU-bound. R3: (1) launch_bounds(256,1) -> no AGPR spill copies
// (R2's VGPR_Count==128 was exactly the cap; unified VGPR/AGPR spills are
// silent VALU moves), (2) attention rows de-duplicated across the 16 lanes.

constexpr int S   = 9;
constexpr int D   = 3;
constexpr int DFF = 2048;
constexpr int L   = 3;
constexpr int G   = 16;          // threads cooperating on one batch element
constexpr int BLK = 256;         // block size
constexpr int BPB = BLK / G;     // batch elements per block = 16
constexpr int FPT = DFF / G;     // f-values per thread = 128
constexpr int PPT = FPT / 2;     // f-pairs per thread = 64
constexpr int NROW = 27;         // attention rows = H*S
constexpr int ATT_STRIDE = 33;   // pad: (grp*33+r)%32 spreads banks
constexpr float EPS = 1e-5f;

typedef float v2f __attribute__((ext_vector_type(2)));
typedef float v4f __attribute__((ext_vector_type(4)));

__device__ __forceinline__ v2f pk_fma(v2f a, v2f b, v2f c) {
    v2f d;
    asm("v_pk_fma_f32 %0, %1, %2, %3" : "=v"(d) : "v"(a), "v"(b), "v"(c));
    return d;
}

__launch_bounds__(BLK, 1)
__global__ void tf_policy_kernel(const float* __restrict__ x,
                                 const float* __restrict__ Wqkv,
                                 const float* __restrict__ bqkv,
                                 const float* __restrict__ Wo,
                                 const float* __restrict__ bo,
                                 const float* __restrict__ g1,
                                 const float* __restrict__ be1,
                                 const float* __restrict__ W1,
                                 const float* __restrict__ bf1,
                                 const float* __restrict__ W2,
                                 const float* __restrict__ bf2,
                                 const float* __restrict__ g2,
                                 const float* __restrict__ be2,
                                 const float* __restrict__ Wfin,
                                 float* __restrict__ out)
{
    // Packed-pair FFN weight layout (pair p covers f=2p, 2p+1):
    //   s_a[p] = {W1[2p][0], W1[2p+1][0], W1[2p][1], W1[2p+1][1]}
    //   s_b[p] = {W1[2p][2], W1[2p+1][2], bf1[2p],   bf1[2p+1]}
    //   s_c[p] = {W2[0][2p], W2[0][2p+1], W2[1][2p], W2[1][2p+1]}
    //   s_d[p] = {W2[2][2p], W2[2][2p+1]}
    __shared__ v4f s_a[DFF / 2];
    __shared__ v4f s_b[DFF / 2];
    __shared__ v4f s_c[DFF / 2];
    __shared__ v2f s_d[DFF / 2];
    __shared__ float s_att[BPB * ATT_STRIDE];   // de-duplicated attention rows

    const int tid = threadIdx.x;
    const int grp = tid >> 4;      // which batch element within block
    const int sub = tid & 15;      // lane within the 16-thread group
    const int b   = blockIdx.x * BPB + grp;

    // per-thread hidden state h[9][3]
    float h[S][D];
    {
        const float* xr = x + (size_t)b * (S * D);
        #pragma unroll
        for (int s = 0; s < S; ++s)
            #pragma unroll
            for (int d = 0; d < D; ++d)
                h[s][d] = xr[s * D + d];
    }

    for (int l = 0; l < L; ++l) {
        __syncthreads();   // protect LDS from previous layer's readers
        // ---- stage packed FFN weights into LDS ----
        {
            const float* w1p = W1  + (size_t)l * DFF * D;
            const float* b1p = bf1 + (size_t)l * DFF;
            const float* w2p = W2  + (size_t)l * D * DFF;
            const v2f* w1v = (const v2f*)w1p;
            const v2f* b1v = (const v2f*)b1p;
            const v2f* c0v = (const v2f*)w2p;
            const v2f* c1v = (const v2f*)(w2p + DFF);
            const v2f* c2v = (const v2f*)(w2p + 2 * DFF);
            for (int p = tid; p < DFF / 2; p += BLK) {
                v2f r0 = w1v[3 * p];        // {W1[2p][0], W1[2p][1]}
                v2f r1 = w1v[3 * p + 1];    // {W1[2p][2], W1[2p+1][0]}
                v2f r2 = w1v[3 * p + 2];    // {W1[2p+1][1], W1[2p+1][2]}
                v2f bb = b1v[p];
                v2f c0 = c0v[p];
                v2f c1 = c1v[p];
                v2f c2 = c2v[p];
                s_a[p] = (v4f){r0.x, r1.y, r0.y, r2.x};
                s_b[p] = (v4f){r1.x, r2.y, bb.x, bb.y};
                s_c[p] = (v4f){c0.x, c0.y, c1.x, c1.y};
                s_d[p] = c2;
            }
        }
        __syncthreads();

        // ---- attention: 27 (head,qs) rows split across the 16 lanes ----
        const float* wq = Wqkv + (size_t)l * (3 * D) * D;   // [9][3]
        const float* bq = bqkv + (size_t)l * (3 * D);
        #pragma unroll
        for (int rr = 0; rr < 2; ++rr) {
            const int r = sub + rr * 16;
            if (r < NROW) {
                const int hh = r / 9;
                const int qs = r % 9;
                // q for this row; k,v for this head only
                float q = fmaf(wq[hh * 3 + 0], h[qs][0],
                          fmaf(wq[hh * 3 + 1], h[qs][1],
                          fmaf(wq[hh * 3 + 2], h[qs][2], bq[hh])));
                float kk[S], vv[S];
                #pragma unroll
                for (int s = 0; s < S; ++s) {
                    kk[s] = fmaf(wq[(3 + hh) * 3 + 0], h[s][0],
                            fmaf(wq[(3 + hh) * 3 + 1], h[s][1],
                            fmaf(wq[(3 + hh) * 3 + 2], h[s][2], bq[3 + hh])));
                    vv[s] = fmaf(wq[(6 + hh) * 3 + 0], h[s][0],
                            fmaf(wq[(6 + hh) * 3 + 1], h[s][1],
                            fmaf(wq[(6 + hh) * 3 + 2], h[s][2], bq[6 + hh])));
                }
                float sc[S];
                float m = -1e30f;
                #pragma unroll
                for (int ks = 0; ks < S; ++ks) {
                    sc[ks] = q * kk[ks];
                    m = fmaxf(m, sc[ks]);
                }
                float sum = 0.f, av = 0.f;
                #pragma unroll
                for (int ks = 0; ks < S; ++ks) {
                    float e = __expf(sc[ks] - m);
                    sum += e;
                    av = fmaf(e, vv[ks], av);
                }
                s_att[grp * ATT_STRIDE + r] = av / sum;   // o[qs][hh], r=hh*9+qs
            }
        }
        __syncthreads();

        // ---- Wo projection + residual + LN1 (redundant per lane; cheap) ----
        {
            float o[S][D];
            #pragma unroll
            for (int hh = 0; hh < D; ++hh)
                #pragma unroll
                for (int s = 0; s < S; ++s)
                    o[s][hh] = s_att[grp * ATT_STRIDE + hh * 9 + s];

            const float* wo  = Wo  + (size_t)l * D * D;
            const float* bop = bo  + (size_t)l * D;
            const float* gp  = g1  + (size_t)l * D;
            const float* bp  = be1 + (size_t)l * D;
            #pragma unroll
            for (int s = 0; s < S; ++s) {
                float t[D];
                #pragma unroll
                for (int dd = 0; dd < D; ++dd)
                    t[dd] = h[s][dd] + bop[dd] +
                            fmaf(wo[dd * 3 + 0], o[s][0],
                            fmaf(wo[dd * 3 + 1], o[s][1],
                                 wo[dd * 3 + 2] * o[s][2]));
                float m  = (t[0] + t[1] + t[2]) * (1.f / 3.f);
                float d0 = t[0] - m, d1 = t[1] - m, d2 = t[2] - m;
                float va = (d0 * d0 + d1 * d1 + d2 * d2) * (1.f / 3.f);
                float r  = rsqrtf(va + EPS);
                h[s][0] = fmaf(d0 * r, gp[0], bp[0]);
                h[s][1] = fmaf(d1 * r, gp[1], bp[1]);
                h[s][2] = fmaf(d2 * r, gp[2], bp[2]);
            }
        }

        // ---- FFN, packed over f-pairs: p = i*16 + sub, i in [0,64) ----
        v2f hb[S][D];                 // h broadcast to both halves (once)
        #pragma unroll
        for (int s = 0; s < S; ++s)
            #pragma unroll
            for (int d = 0; d < D; ++d)
                hb[s][d] = (v2f){h[s][d], h[s][d]};

        v2f acc2[S][D];
        #pragma unroll
        for (int s = 0; s < S; ++s)
            #pragma unroll
            for (int d = 0; d < D; ++d)
                acc2[s][d] = (v2f){0.f, 0.f};

        #pragma unroll 4
        for (int i = 0; i < PPT; ++i) {
            const int p = i * G + sub;
            const v4f A  = s_a[p];
            const v4f Bv = s_b[p];
            const v4f C  = s_c[p];
            const v2f Dz = s_d[p];
            const v2f w1x = A.xy,  w1y = A.zw;
            const v2f w1z = Bv.xy, w1b = Bv.zw;
            const v2f w2x = C.xy,  w2y = C.zw;
            #pragma unroll
            for (int s = 0; s < S; ++s) {
                v2f t = pk_fma(w1x, hb[s][0],
                        pk_fma(w1y, hb[s][1],
                        pk_fma(w1z, hb[s][2], w1b)));
                t.x = fmaxf(t.x, 0.f);
                t.y = fmaxf(t.y, 0.f);
                acc2[s][0] = pk_fma(w2x, t, acc2[s][0]);
                acc2[s][1] = pk_fma(w2y, t, acc2[s][1]);
                acc2[s][2] = pk_fma(Dz, t, acc2[s][2]);
            }
        }

        // ---- collapse pair halves, then butterfly-reduce across 16 lanes ----
        float acc[S][D];
        #pragma unroll
        for (int s = 0; s < S; ++s)
            #pragma unroll
            for (int d = 0; d < D; ++d)
                acc[s][d] = acc2[s][d].x + acc2[s][d].y;

        #pragma unroll
        for (int mask = 1; mask < G; mask <<= 1) {
            #pragma unroll
            for (int s = 0; s < S; ++s)
                #pragma unroll
                for (int d = 0; d < D; ++d)
                    acc[s][d] += __shfl_xor(acc[s][d], mask, 64);
        }

        // ---- bf2 + residual + LN2 ----
        {
            const float* b2p = bf2 + (size_t)l * D;
            const float* gp  = g2  + (size_t)l * D;
            const float* bp  = be2 + (size_t)l * D;
            #pragma unroll
            for (int s = 0; s < S; ++s) {
                float t[D];
                #pragma unroll
                for (int dd = 0; dd < D; ++dd)
                    t[dd] = h[s][dd] + acc[s][dd] + b2p[dd];
                float m  = (t[0] + t[1] + t[2]) * (1.f / 3.f);
                float d0 = t[0] - m, d1 = t[1] - m, d2 = t[2] - m;
                float va = (d0 * d0 + d1 * d1 + d2 * d2) * (1.f / 3.f);
                float r  = rsqrtf(va + EPS);
                h[s][0] = fmaf(d0 * r, gp[0], bp[0]);
                h[s][1] = fmaf(d1 * r, gp[1], bp[1]);
                h[s][2] = fmaf(d2 * r, gp[2], bp[2]);
            }
        }
    }

    // ---- epilogue: z = softmax(h@W) per token, u = prod_s z, softmax(u) ----
    if (sub == 0) {
        float u[S];
        #pragma unroll
        for (int n = 0; n < S; ++n) u[n] = 1.f;
        #pragma unroll
        for (int s = 0; s < S; ++s) {
            float z[S];
            float m = -1e30f;
            #pragma unroll
            for (int n = 0; n < S; ++n) {
                z[n] = fmaf(h[s][0], Wfin[0 * S + n],
                       fmaf(h[s][1], Wfin[1 * S + n],
                            h[s][2] * Wfin[2 * S + n]));
                m = fmaxf(m, z[n]);
            }
            float sum = 0.f;
            #pragma unroll
            for (int n = 0; n < S; ++n) { z[n] = __expf(z[n] - m); sum += z[n]; }
            float inv = 1.f / sum;
            #pragma unroll
            for (int n = 0; n < S; ++n) u[n] *= z[n] * inv;
        }
        float m = -1e30f;
        #pragma unroll
        for (int n = 0; n < S; ++n) m = fmaxf(m, u[n]);
        float e[S];
        float sum = 0.f;
        #pragma unroll
        for (int n = 0; n < S; ++n) { e[n] = __expf(u[n] - m); sum += e[n]; }
        float inv = 1.f / sum;
        float* op = out + (size_t)b * S;
        #pragma unroll
        for (int n = 0; n < S; ++n) op[n] = e[n] * inv;
    }
}

extern "C" void kernel_launch(void* const* d_in, const int* in_sizes, int n_in,
                              void* d_out, int out_size, void* d_ws, size_t ws_size,
                              hipStream_t stream)
{
    const float* x    = (const float*)d_in[0];
    const float* Wqkv = (const float*)d_in[1];
    const float* bqkv = (const float*)d_in[2];
    const float* Wo   = (const float*)d_in[3];
    const float* bo   = (const float*)d_in[4];
    const float* g1   = (const float*)d_in[5];
    const float* be1  = (const float*)d_in[6];
    const float* W1   = (const float*)d_in[7];
    const float* bf1  = (const float*)d_in[8];
    const float* W2   = (const float*)d_in[9];
    const float* bf2  = (const float*)d_in[10];
    const float* g2   = (const float*)d_in[11];
    const float* be2  = (const float*)d_in[12];
    const float* Wfin = (const float*)d_in[13];
    float* out = (float*)d_out;

    const int B = in_sizes[0] / (S * D);       // 8192
    const int nblocks = B / BPB;               // 512

    tf_policy_kernel<<<nblocks, BLK, 0, stream>>>(
        x, Wqkv, bqkv, Wo, bo, g1, be1, W1, bf1, W2, bf2, g2, be2, Wfin, out);
}

// Round 4
// 104.127 us; speedup vs baseline: 1.1971x; 1.0565x over previous
//
#include <hip/hip_runtime.h>
#include <math.h>

// PolicyGradient_28819230556839: 3-layer post-norm transformer encoder,
// B=8192, S=9, D=3, H=3 (head dim 1), DFF=2048, then logits->softmax->prod->softmax.
// fp32 VALU-bound. R4: tied-operand v_pk_fma_f32 asm ("+v") so results land
// in-place — R2/R3's untied "=v" asm caused ~2.9x v_mov bloat (confirmed by
// busy-cycle arithmetic vs static instruction count; R1 matched at 1.19x).

constexpr int S   = 9;
constexpr int D   = 3;
constexpr int DFF = 2048;
constexpr int L   = 3;
constexpr int G   = 16;          // threads cooperating on one batch element
constexpr int BLK = 256;         // block size
constexpr int BPB = BLK / G;     // batch elements per block = 16
constexpr int FPT = DFF / G;     // f-values per thread = 128
constexpr int PPT = FPT / 2;     // f-pairs per thread = 64
constexpr int NROW = 27;         // attention rows = H*S
constexpr int ATT_STRIDE = 33;
constexpr float EPS = 1e-5f;

typedef float v2f __attribute__((ext_vector_type(2)));
typedef float v4f __attribute__((ext_vector_type(4)));

// d = a*b + c, fresh dest (single instr, no movs: inputs stay live elsewhere)
#define PK_FMA_INIT(d, a, bb, c) \
    asm("v_pk_fma_f32 %0, %1, %2, %3" : "=v"(d) : "v"(a), "v"(bb), "v"(c))
// d = a*b + d, tied dest (guaranteed in-place, zero movs)
#define PK_FMA_ACC(d, a, bb) \
    asm("v_pk_fma_f32 %0, %1, %2, %0" : "+v"(d) : "v"(a), "v"(bb))

__launch_bounds__(BLK, 1)
__global__ void tf_policy_kernel(const float* __restrict__ x,
                                 const float* __restrict__ Wqkv,
                                 const float* __restrict__ bqkv,
                                 const float* __restrict__ Wo,
                                 const float* __restrict__ bo,
                                 const float* __restrict__ g1,
                                 const float* __restrict__ be1,
                                 const float* __restrict__ W1,
                                 const float* __restrict__ bf1,
                                 const float* __restrict__ W2,
                                 const float* __restrict__ bf2,
                                 const float* __restrict__ g2,
                                 const float* __restrict__ be2,
                                 const float* __restrict__ Wfin,
                                 float* __restrict__ out)
{
    // Packed-pair FFN weight layout (pair p covers f=2p, 2p+1):
    //   s_a[p] = {W1[2p][0], W1[2p+1][0], W1[2p][1], W1[2p+1][1]}
    //   s_b[p] = {W1[2p][2], W1[2p+1][2], bf1[2p],   bf1[2p+1]}
    //   s_c[p] = {W2[0][2p], W2[0][2p+1], W2[1][2p], W2[1][2p+1]}
    //   s_d[p] = {W2[2][2p], W2[2][2p+1]}
    __shared__ v4f s_a[DFF / 2];
    __shared__ v4f s_b[DFF / 2];
    __shared__ v4f s_c[DFF / 2];
    __shared__ v2f s_d[DFF / 2];
    __shared__ float s_att[BPB * ATT_STRIDE];   // de-duplicated attention rows

    const int tid = threadIdx.x;
    const int grp = tid >> 4;      // which batch element within block
    const int sub = tid & 15;      // lane within the 16-thread group
    const int b   = blockIdx.x * BPB + grp;

    // per-thread hidden state h[9][3]
    float h[S][D];
    {
        const float* xr = x + (size_t)b * (S * D);
        #pragma unroll
        for (int s = 0; s < S; ++s)
            #pragma unroll
            for (int d = 0; d < D; ++d)
                h[s][d] = xr[s * D + d];
    }

    for (int l = 0; l < L; ++l) {
        __syncthreads();   // protect LDS from previous layer's readers
        // ---- stage packed FFN weights into LDS ----
        {
            const float* w1p = W1  + (size_t)l * DFF * D;
            const float* b1p = bf1 + (size_t)l * DFF;
            const float* w2p = W2  + (size_t)l * D * DFF;
            const v2f* w1v = (const v2f*)w1p;
            const v2f* b1v = (const v2f*)b1p;
            const v2f* c0v = (const v2f*)w2p;
            const v2f* c1v = (const v2f*)(w2p + DFF);
            const v2f* c2v = (const v2f*)(w2p + 2 * DFF);
            for (int p = tid; p < DFF / 2; p += BLK) {
                v2f r0 = w1v[3 * p];        // {W1[2p][0], W1[2p][1]}
                v2f r1 = w1v[3 * p + 1];    // {W1[2p][2], W1[2p+1][0]}
                v2f r2 = w1v[3 * p + 2];    // {W1[2p+1][1], W1[2p+1][2]}
                v2f bb = b1v[p];
                v2f c0 = c0v[p];
                v2f c1 = c1v[p];
                v2f c2 = c2v[p];
                s_a[p] = (v4f){r0.x, r1.y, r0.y, r2.x};
                s_b[p] = (v4f){r1.x, r2.y, bb.x, bb.y};
                s_c[p] = (v4f){c0.x, c0.y, c1.x, c1.y};
                s_d[p] = c2;
            }
        }
        __syncthreads();

        // ---- attention: 27 (head,qs) rows split across the 16 lanes ----
        const float* wq = Wqkv + (size_t)l * (3 * D) * D;   // [9][3]
        const float* bq = bqkv + (size_t)l * (3 * D);
        #pragma unroll
        for (int rr = 0; rr < 2; ++rr) {
            const int r = sub + rr * 16;
            if (r < NROW) {
                const int hh = r / 9;
                const int qs = r % 9;
                float q = fmaf(wq[hh * 3 + 0], h[qs][0],
                          fmaf(wq[hh * 3 + 1], h[qs][1],
                          fmaf(wq[hh * 3 + 2], h[qs][2], bq[hh])));
                float kk[S], vv[S];
                #pragma unroll
                for (int s = 0; s < S; ++s) {
                    kk[s] = fmaf(wq[(3 + hh) * 3 + 0], h[s][0],
                            fmaf(wq[(3 + hh) * 3 + 1], h[s][1],
                            fmaf(wq[(3 + hh) * 3 + 2], h[s][2], bq[3 + hh])));
                    vv[s] = fmaf(wq[(6 + hh) * 3 + 0], h[s][0],
                            fmaf(wq[(6 + hh) * 3 + 1], h[s][1],
                            fmaf(wq[(6 + hh) * 3 + 2], h[s][2], bq[6 + hh])));
                }
                float sc[S];
                float m = -1e30f;
                #pragma unroll
                for (int ks = 0; ks < S; ++ks) {
                    sc[ks] = q * kk[ks];
                    m = fmaxf(m, sc[ks]);
                }
                float sum = 0.f, av = 0.f;
                #pragma unroll
                for (int ks = 0; ks < S; ++ks) {
                    float e = __expf(sc[ks] - m);
                    sum += e;
                    av = fmaf(e, vv[ks], av);
                }
                s_att[grp * ATT_STRIDE + r] = av / sum;   // o[qs][hh], r=hh*9+qs
            }
        }
        __syncthreads();

        // ---- Wo projection + residual + LN1, writing into packed hb ----
        v2f hb[S][D];     // {v,v} pairs; .x doubles as the scalar h
        {
            float o[S][D];
            #pragma unroll
            for (int hh = 0; hh < D; ++hh)
                #pragma unroll
                for (int s = 0; s < S; ++s)
                    o[s][hh] = s_att[grp * ATT_STRIDE + hh * 9 + s];

            const float* wo  = Wo  + (size_t)l * D * D;
            const float* bop = bo  + (size_t)l * D;
            const float* gp  = g1  + (size_t)l * D;
            const float* bp  = be1 + (size_t)l * D;
            #pragma unroll
            for (int s = 0; s < S; ++s) {
                float t[D];
                #pragma unroll
                for (int dd = 0; dd < D; ++dd)
                    t[dd] = h[s][dd] + bop[dd] +
                            fmaf(wo[dd * 3 + 0], o[s][0],
                            fmaf(wo[dd * 3 + 1], o[s][1],
                                 wo[dd * 3 + 2] * o[s][2]));
                float m  = (t[0] + t[1] + t[2]) * (1.f / 3.f);
                float d0 = t[0] - m, d1 = t[1] - m, d2 = t[2] - m;
                float va = (d0 * d0 + d1 * d1 + d2 * d2) * (1.f / 3.f);
                float r  = rsqrtf(va + EPS);
                float n0 = fmaf(d0 * r, gp[0], bp[0]);
                float n1 = fmaf(d1 * r, gp[1], bp[1]);
                float n2 = fmaf(d2 * r, gp[2], bp[2]);
                hb[s][0] = (v2f){n0, n0};
                hb[s][1] = (v2f){n1, n1};
                hb[s][2] = (v2f){n2, n2};
            }
        }

        // ---- FFN, packed over f-pairs: p = i*16 + sub, i in [0,64) ----
        v2f acc2[S][D];
        #pragma unroll
        for (int s = 0; s < S; ++s)
            #pragma unroll
            for (int d = 0; d < D; ++d)
                acc2[s][d] = (v2f){0.f, 0.f};

        #pragma unroll 2
        for (int i = 0; i < PPT; ++i) {
            const int p = i * G + sub;
            const v4f A  = s_a[p];
            const v4f Bv = s_b[p];
            const v4f C  = s_c[p];
            const v2f Dz = s_d[p];
            const v2f w1x = A.xy,  w1y = A.zw;
            const v2f w1z = Bv.xy, w1b = Bv.zw;
            const v2f w2x = C.xy,  w2y = C.zw;
            #pragma unroll
            for (int s = 0; s < S; ++s) {
                v2f t;
                PK_FMA_INIT(t, w1z, hb[s][2], w1b);
                PK_FMA_ACC(t, w1y, hb[s][1]);
                PK_FMA_ACC(t, w1x, hb[s][0]);
                t.x = fmaxf(t.x, 0.f);
                t.y = fmaxf(t.y, 0.f);
                PK_FMA_ACC(acc2[s][0], w2x, t);
                PK_FMA_ACC(acc2[s][1], w2y, t);
                PK_FMA_ACC(acc2[s][2], Dz,  t);
            }
        }

        // ---- collapse pair halves, then butterfly-reduce across 16 lanes ----
        float acc[S][D];
        #pragma unroll
        for (int s = 0; s < S; ++s)
            #pragma unroll
            for (int d = 0; d < D; ++d)
                acc[s][d] = acc2[s][d].x + acc2[s][d].y;

        #pragma unroll
        for (int mask = 1; mask < G; mask <<= 1) {
            #pragma unroll
            for (int s = 0; s < S; ++s)
                #pragma unroll
                for (int d = 0; d < D; ++d)
                    acc[s][d] += __shfl_xor(acc[s][d], mask, 64);
        }

        // ---- bf2 + residual (from hb.x) + LN2 -> scalar h for next layer ----
        {
            const float* b2p = bf2 + (size_t)l * D;
            const float* gp  = g2  + (size_t)l * D;
            const float* bp  = be2 + (size_t)l * D;
            #pragma unroll
            for (int s = 0; s < S; ++s) {
                float t[D];
                #pragma unroll
                for (int dd = 0; dd < D; ++dd)
                    t[dd] = hb[s][dd].x + acc[s][dd] + b2p[dd];
                float m  = (t[0] + t[1] + t[2]) * (1.f / 3.f);
                float d0 = t[0] - m, d1 = t[1] - m, d2 = t[2] - m;
                float va = (d0 * d0 + d1 * d1 + d2 * d2) * (1.f / 3.f);
                float r  = rsqrtf(va + EPS);
                h[s][0] = fmaf(d0 * r, gp[0], bp[0]);
                h[s][1] = fmaf(d1 * r, gp[1], bp[1]);
                h[s][2] = fmaf(d2 * r, gp[2], bp[2]);
            }
        }
    }

    // ---- epilogue: z = softmax(h@W) per token, u = prod_s z, softmax(u) ----
    if (sub == 0) {
        float u[S];
        #pragma unroll
        for (int n = 0; n < S; ++n) u[n] = 1.f;
        #pragma unroll
        for (int s = 0; s < S; ++s) {
            float z[S];
            float m = -1e30f;
            #pragma unroll
            for (int n = 0; n < S; ++n) {
                z[n] = fmaf(h[s][0], Wfin[0 * S + n],
                       fmaf(h[s][1], Wfin[1 * S + n],
                            h[s][2] * Wfin[2 * S + n]));
                m = fmaxf(m, z[n]);
            }
            float sum = 0.f;
            #pragma unroll
            for (int n = 0; n < S; ++n) { z[n] = __expf(z[n] - m); sum += z[n]; }
            float inv = 1.f / sum;
            #pragma unroll
            for (int n = 0; n < S; ++n) u[n] *= z[n] * inv;
        }
        float m = -1e30f;
        #pragma unroll
        for (int n = 0; n < S; ++n) m = fmaxf(m, u[n]);
        float e[S];
        float sum = 0.f;
        #pragma unroll
        for (int n = 0; n < S; ++n) { e[n] = __expf(u[n] - m); sum += e[n]; }
        float inv = 1.f / sum;
        float* op = out + (size_t)b * S;
        #pragma unroll
        for (int n = 0; n < S; ++n) op[n] = e[n] * inv;
    }
}

extern "C" void kernel_launch(void* const* d_in, const int* in_sizes, int n_in,
                              void* d_out, int out_size, void* d_ws, size_t ws_size,
                              hipStream_t stream)
{
    const float* x    = (const float*)d_in[0];
    const float* Wqkv = (const float*)d_in[1];
    const float* bqkv = (const float*)d_in[2];
    const float* Wo   = (const float*)d_in[3];
    const float* bo   = (const float*)d_in[4];
    const float* g1   = (const float*)d_in[5];
    const float* be1  = (const float*)d_in[6];
    const float* W1   = (const float*)d_in[7];
    const float* bf1  = (const float*)d_in[8];
    const float* W2   = (const float*)d_in[9];
    const float* bf2  = (const float*)d_in[10];
    const float* g2   = (const float*)d_in[11];
    const float* be2  = (const float*)d_in[12];
    const float* Wfin = (const float*)d_in[13];
    float* out = (float*)d_out;

    const int B = in_sizes[0] / (S * D);       // 8192
    const int nblocks = B / BPB;               // 512

    tf_policy_kernel<<<nblocks, BLK, 0, stream>>>(
        x, Wqkv, bqkv, Wo, bo, g1, be1, W1, bf1, W2, bf2, g2, be2, Wfin, out);
}

// Round 5
// 103.398 us; speedup vs baseline: 1.2056x; 1.0071x over previous
//
#include <hip/hip_runtime.h>
#include <math.h>

// PolicyGradient_28819230556839: 3-layer post-norm transformer encoder,
// B=8192, S=9, D=3, H=3 (head dim 1), DFF=2048, then logits->softmax->prod->softmax.
// fp32 VALU-bound. R5: occupancy 2->4 waves/SIMD (BLK=512, 1 block/CU,
// 16 waves/CU). Note: v_pk_fma_f32 is HALF-RATE on CDNA4 (157.3 TF spec IS
// the scalar fma rate) — packing is issue-neutral; the gap to the ~45us
// issue floor is latency-hiding, hence this round attacks occupancy.

constexpr int S   = 9;
constexpr int D   = 3;
constexpr int DFF = 2048;
constexpr int L   = 3;
constexpr int G   = 16;          // threads cooperating on one batch element
constexpr int BLK = 512;         // block size (8 waves -> 16 waves/CU at 1 block/CU)
constexpr int BPB = BLK / G;     // batch elements per block = 32
constexpr int FPT = DFF / G;     // f-values per thread = 128
constexpr int PPT = FPT / 2;     // f-pairs per thread = 64
constexpr int NROW = 27;         // attention rows = H*S
constexpr int ATT_STRIDE = 33;
constexpr float EPS = 1e-5f;

typedef float v2f __attribute__((ext_vector_type(2)));
typedef float v4f __attribute__((ext_vector_type(4)));

// d = a*b + c, fresh dest
#define PK_FMA_INIT(d, a, bb, c) \
    asm("v_pk_fma_f32 %0, %1, %2, %3" : "=v"(d) : "v"(a), "v"(bb), "v"(c))
// d = a*b + d, tied dest (in-place)
#define PK_FMA_ACC(d, a, bb) \
    asm("v_pk_fma_f32 %0, %1, %2, %0" : "+v"(d) : "v"(a), "v"(bb))

__launch_bounds__(BLK, 1)
__global__ void tf_policy_kernel(const float* __restrict__ x,
                                 const float* __restrict__ Wqkv,
                                 const float* __restrict__ bqkv,
                                 const float* __restrict__ Wo,
                                 const float* __restrict__ bo,
                                 const float* __restrict__ g1,
                                 const float* __restrict__ be1,
                                 const float* __restrict__ W1,
                                 const float* __restrict__ bf1,
                                 const float* __restrict__ W2,
                                 const float* __restrict__ bf2,
                                 const float* __restrict__ g2,
                                 const float* __restrict__ be2,
                                 const float* __restrict__ Wfin,
                                 float* __restrict__ out)
{
    // Packed-pair FFN weight layout (pair p covers f=2p, 2p+1):
    //   s_a[p] = {W1[2p][0], W1[2p+1][0], W1[2p][1], W1[2p+1][1]}
    //   s_b[p] = {W1[2p][2], W1[2p+1][2], bf1[2p],   bf1[2p+1]}
    //   s_c[p] = {W2[0][2p], W2[0][2p+1], W2[1][2p], W2[1][2p+1]}
    //   s_d[p] = {W2[2][2p], W2[2][2p+1]}
    __shared__ v4f s_a[DFF / 2];
    __shared__ v4f s_b[DFF / 2];
    __shared__ v4f s_c[DFF / 2];
    __shared__ v2f s_d[DFF / 2];
    __shared__ float s_att[BPB * ATT_STRIDE];   // de-duplicated attention rows

    const int tid = threadIdx.x;
    const int grp = tid >> 4;      // which batch element within block
    const int sub = tid & 15;      // lane within the 16-thread group
    const int b   = blockIdx.x * BPB + grp;

    // per-thread hidden state h[9][3]
    float h[S][D];
    {
        const float* xr = x + (size_t)b * (S * D);
        #pragma unroll
        for (int s = 0; s < S; ++s)
            #pragma unroll
            for (int d = 0; d < D; ++d)
                h[s][d] = xr[s * D + d];
    }

    for (int l = 0; l < L; ++l) {
        __syncthreads();   // protect LDS from previous layer's readers
        // ---- stage packed FFN weights into LDS ----
        {
            const float* w1p = W1  + (size_t)l * DFF * D;
            const float* b1p = bf1 + (size_t)l * DFF;
            const float* w2p = W2  + (size_t)l * D * DFF;
            const v2f* w1v = (const v2f*)w1p;
            const v2f* b1v = (const v2f*)b1p;
            const v2f* c0v = (const v2f*)w2p;
            const v2f* c1v = (const v2f*)(w2p + DFF);
            const v2f* c2v = (const v2f*)(w2p + 2 * DFF);
            for (int p = tid; p < DFF / 2; p += BLK) {
                v2f r0 = w1v[3 * p];        // {W1[2p][0], W1[2p][1]}
                v2f r1 = w1v[3 * p + 1];    // {W1[2p][2], W1[2p+1][0]}
                v2f r2 = w1v[3 * p + 2];    // {W1[2p+1][1], W1[2p+1][2]}
                v2f bb = b1v[p];
                v2f c0 = c0v[p];
                v2f c1 = c1v[p];
                v2f c2 = c2v[p];
                s_a[p] = (v4f){r0.x, r1.y, r0.y, r2.x};
                s_b[p] = (v4f){r1.x, r2.y, bb.x, bb.y};
                s_c[p] = (v4f){c0.x, c0.y, c1.x, c1.y};
                s_d[p] = c2;
            }
        }
        __syncthreads();

        // ---- attention: 27 (head,qs) rows split across the 16 lanes ----
        const float* wq = Wqkv + (size_t)l * (3 * D) * D;   // [9][3]
        const float* bq = bqkv + (size_t)l * (3 * D);
        #pragma unroll
        for (int rr = 0; rr < 2; ++rr) {
            const int r = sub + rr * 16;
            if (r < NROW) {
                const int hh = r / 9;
                const int qs = r % 9;
                float q = fmaf(wq[hh * 3 + 0], h[qs][0],
                          fmaf(wq[hh * 3 + 1], h[qs][1],
                          fmaf(wq[hh * 3 + 2], h[qs][2], bq[hh])));
                float kk[S], vv[S];
                #pragma unroll
                for (int s = 0; s < S; ++s) {
                    kk[s] = fmaf(wq[(3 + hh) * 3 + 0], h[s][0],
                            fmaf(wq[(3 + hh) * 3 + 1], h[s][1],
                            fmaf(wq[(3 + hh) * 3 + 2], h[s][2], bq[3 + hh])));
                    vv[s] = fmaf(wq[(6 + hh) * 3 + 0], h[s][0],
                            fmaf(wq[(6 + hh) * 3 + 1], h[s][1],
                            fmaf(wq[(6 + hh) * 3 + 2], h[s][2], bq[6 + hh])));
                }
                float sc[S];
                float m = -1e30f;
                #pragma unroll
                for (int ks = 0; ks < S; ++ks) {
                    sc[ks] = q * kk[ks];
                    m = fmaxf(m, sc[ks]);
                }
                float sum = 0.f, av = 0.f;
                #pragma unroll
                for (int ks = 0; ks < S; ++ks) {
                    float e = __expf(sc[ks] - m);
                    sum += e;
                    av = fmaf(e, vv[ks], av);
                }
                s_att[grp * ATT_STRIDE + r] = av / sum;   // o[qs][hh], r=hh*9+qs
            }
        }
        __syncthreads();

        // ---- Wo projection + residual + LN1, writing into packed hb ----
        v2f hb[S][D];     // {v,v} pairs; .x doubles as the scalar h
        {
            float o[S][D];
            #pragma unroll
            for (int hh = 0; hh < D; ++hh)
                #pragma unroll
                for (int s = 0; s < S; ++s)
                    o[s][hh] = s_att[grp * ATT_STRIDE + hh * 9 + s];

            const float* wo  = Wo  + (size_t)l * D * D;
            const float* bop = bo  + (size_t)l * D;
            const float* gp  = g1  + (size_t)l * D;
            const float* bp  = be1 + (size_t)l * D;
            #pragma unroll
            for (int s = 0; s < S; ++s) {
                float t[D];
                #pragma unroll
                for (int dd = 0; dd < D; ++dd)
                    t[dd] = h[s][dd] + bop[dd] +
                            fmaf(wo[dd * 3 + 0], o[s][0],
                            fmaf(wo[dd * 3 + 1], o[s][1],
                                 wo[dd * 3 + 2] * o[s][2]));
                float m  = (t[0] + t[1] + t[2]) * (1.f / 3.f);
                float d0 = t[0] - m, d1 = t[1] - m, d2 = t[2] - m;
                float va = (d0 * d0 + d1 * d1 + d2 * d2) * (1.f / 3.f);
                float r  = rsqrtf(va + EPS);
                float n0 = fmaf(d0 * r, gp[0], bp[0]);
                float n1 = fmaf(d1 * r, gp[1], bp[1]);
                float n2 = fmaf(d2 * r, gp[2], bp[2]);
                hb[s][0] = (v2f){n0, n0};
                hb[s][1] = (v2f){n1, n1};
                hb[s][2] = (v2f){n2, n2};
            }
        }

        // ---- FFN, packed over f-pairs: p = i*16 + sub, i in [0,64) ----
        v2f acc2[S][D];
        #pragma unroll
        for (int s = 0; s < S; ++s)
            #pragma unroll
            for (int d = 0; d < D; ++d)
                acc2[s][d] = (v2f){0.f, 0.f};

        #pragma unroll 2
        for (int i = 0; i < PPT; ++i) {
            const int p = i * G + sub;
            const v4f A  = s_a[p];
            const v4f Bv = s_b[p];
            const v4f C  = s_c[p];
            const v2f Dz = s_d[p];
            const v2f w1x = A.xy,  w1y = A.zw;
            const v2f w1z = Bv.xy, w1b = Bv.zw;
            const v2f w2x = C.xy,  w2y = C.zw;
            #pragma unroll
            for (int s = 0; s < S; ++s) {
                v2f t;
                PK_FMA_INIT(t, w1z, hb[s][2], w1b);
                PK_FMA_ACC(t, w1y, hb[s][1]);
                PK_FMA_ACC(t, w1x, hb[s][0]);
                t.x = fmaxf(t.x, 0.f);
                t.y = fmaxf(t.y, 0.f);
                PK_FMA_ACC(acc2[s][0], w2x, t);
                PK_FMA_ACC(acc2[s][1], w2y, t);
                PK_FMA_ACC(acc2[s][2], Dz,  t);
            }
        }

        // ---- collapse pair halves, then butterfly-reduce across 16 lanes ----
        float acc[S][D];
        #pragma unroll
        for (int s = 0; s < S; ++s)
            #pragma unroll
            for (int d = 0; d < D; ++d)
                acc[s][d] = acc2[s][d].x + acc2[s][d].y;

        #pragma unroll
        for (int mask = 1; mask < G; mask <<= 1) {
            #pragma unroll
            for (int s = 0; s < S; ++s)
                #pragma unroll
                for (int d = 0; d < D; ++d)
                    acc[s][d] += __shfl_xor(acc[s][d], mask, 64);
        }

        // ---- bf2 + residual (from hb.x) + LN2 -> scalar h for next layer ----
        {
            const float* b2p = bf2 + (size_t)l * D;
            const float* gp  = g2  + (size_t)l * D;
            const float* bp  = be2 + (size_t)l * D;
            #pragma unroll
            for (int s = 0; s < S; ++s) {
                float t[D];
                #pragma unroll
                for (int dd = 0; dd < D; ++dd)
                    t[dd] = hb[s][dd].x + acc[s][dd] + b2p[dd];
                float m  = (t[0] + t[1] + t[2]) * (1.f / 3.f);
                float d0 = t[0] - m, d1 = t[1] - m, d2 = t[2] - m;
                float va = (d0 * d0 + d1 * d1 + d2 * d2) * (1.f / 3.f);
                float r  = rsqrtf(va + EPS);
                h[s][0] = fmaf(d0 * r, gp[0], bp[0]);
                h[s][1] = fmaf(d1 * r, gp[1], bp[1]);
                h[s][2] = fmaf(d2 * r, gp[2], bp[2]);
            }
        }
    }

    // ---- epilogue: z = softmax(h@W) per token, u = prod_s z, softmax(u) ----
    if (sub == 0) {
        float u[S];
        #pragma unroll
        for (int n = 0; n < S; ++n) u[n] = 1.f;
        #pragma unroll
        for (int s = 0; s < S; ++s) {
            float z[S];
            float m = -1e30f;
            #pragma unroll
            for (int n = 0; n < S; ++n) {
                z[n] = fmaf(h[s][0], Wfin[0 * S + n],
                       fmaf(h[s][1], Wfin[1 * S + n],
                            h[s][2] * Wfin[2 * S + n]));
                m = fmaxf(m, z[n]);
            }
            float sum = 0.f;
            #pragma unroll
            for (int n = 0; n < S; ++n) { z[n] = __expf(z[n] - m); sum += z[n]; }
            float inv = 1.f / sum;
            #pragma unroll
            for (int n = 0; n < S; ++n) u[n] *= z[n] * inv;
        }
        float m = -1e30f;
        #pragma unroll
        for (int n = 0; n < S; ++n) m = fmaxf(m, u[n]);
        float e[S];
        float sum = 0.f;
        #pragma unroll
        for (int n = 0; n < S; ++n) { e[n] = __expf(u[n] - m); sum += e[n]; }
        float inv = 1.f / sum;
        float* op = out + (size_t)b * S;
        #pragma unroll
        for (int n = 0; n < S; ++n) op[n] = e[n] * inv;
    }
}

extern "C" void kernel_launch(void* const* d_in, const int* in_sizes, int n_in,
                              void* d_out, int out_size, void* d_ws, size_t ws_size,
                              hipStream_t stream)
{
    const float* x    = (const float*)d_in[0];
    const float* Wqkv = (const float*)d_in[1];
    const float* bqkv = (const float*)d_in[2];
    const float* Wo   = (const float*)d_in[3];
    const float* bo   = (const float*)d_in[4];
    const float* g1   = (const float*)d_in[5];
    const float* be1  = (const float*)d_in[6];
    const float* W1   = (const float*)d_in[7];
    const float* bf1  = (const float*)d_in[8];
    const float* W2   = (const float*)d_in[9];
    const float* bf2  = (const float*)d_in[10];
    const float* g2   = (const float*)d_in[11];
    const float* be2  = (const float*)d_in[12];
    const float* Wfin = (const float*)d_in[13];
    float* out = (float*)d_out;

    const int B = in_sizes[0] / (S * D);       // 8192
    const int nblocks = B / BPB;               // 256 -> 1 block/CU, 16 waves/CU

    tf_policy_kernel<<<nblocks, BLK, 0, stream>>>(
        x, Wqkv, bqkv, Wo, bo, g1, be1, W1, bf1, W2, bf2, g2, be2, Wfin, out);
}